// Round 1
// baseline (407.105 us; speedup 1.0000x reference)
//
#include <hip/hip_runtime.h>

// Fused SSIM, B=64, C=1, 512x512 fp32, 11x11 separable Gaussian.
// R9 = R8 + occupancy doubling. R8 was latency/barrier-bound: LDS 67KB ->
// 2 blocks/CU -> 4 waves/SIMD; VALUBusy 51%, occupancy 33%.
// R9: BH=32, CHUNK=4 -> LDS 33.5KB -> 4 blocks/CU, grid 16x64 = 1024 blocks
// = 4/CU exactly; __launch_bounds__(512,8) caps VGPR at 64 so all 32 waves/CU
// are resident. Same per-pixel math; per-chunk window is 14 rows.
// Bank class preserved: h-conv lane mapping rr = tid&3 (row varies within the
// wave), c0 = (tid>>2)*4; row stride 522 f32x2 = 1044 words = 20 mod 32 ->
// start banks {20*rr + 8*m} = {0,4,..,28}, 8 lanes each, closed under +16
// (the R6-verified zero-conflict class). Writes unchanged (uniform 4/bank).

#define IMG 512
#define BH 32            // band height (output rows per block)
#define CHUNK 4
#define NCHUNK (BH / CHUNK)     // 8
#define SROW 522         // f32x2 per row per plane: 5 pad + 512 + 5 pad
#define NTHREADS 512
#define GRIDX (IMG / BH)        // 16

typedef __attribute__((ext_vector_type(2))) float f32x2;

static __device__ __forceinline__ f32x2 pk_fma(f32x2 a, f32x2 b, f32x2 c) {
    f32x2 d;
    asm("v_pk_fma_f32 %0, %1, %2, %3" : "=v"(d) : "v"(a), "v"(b), "v"(c));
    return d;
}
static __device__ __forceinline__ f32x2 pk_mul(f32x2 a, f32x2 b) {
    f32x2 d;
    asm("v_pk_mul_f32 %0, %1, %2" : "=v"(d) : "v"(a), "v"(b));
    return d;
}

__global__ __launch_bounds__(NTHREADS, 8) void ssim_band(
    const float* __restrict__ x, const float* __restrict__ y,
    const float* __restrict__ win, float* __restrict__ partial)
{
    __shared__ __align__(16) f32x2 vab[CHUNK][SROW];   // v-conv of (s, d)
    __shared__ __align__(16) f32x2 vqq[CHUNK][SROW];   // v-conv of (s^2, d^2)
    __shared__ float sg[11];
    __shared__ float redbuf[NTHREADS / 64];

    const int tid = threadIdx.x;

    // 1D kernel g[i] = row sums of the 2D window (exact since sum(g)==1).
    if (tid < 11) {
        float s = 0.f;
        #pragma unroll
        for (int j = 0; j < 11; ++j) s += win[tid * 11 + j];
        sg[tid] = s;
    }
    // Zero the pad columns once (LDS is re-poisoned every launch).
    // 2 planes * 4 rows * 10 pad cols = 80 entries.
    if (tid < 80) {
        int plane = tid / 40, rem = tid % 40, row = rem / 10, pc = rem % 10;
        int cc = (pc < 5) ? pc : (512 + pc);   // stored cols 0..4, 517..521
        f32x2 z = (f32x2)(0.f);
        if (plane == 0) vab[row][cc] = z; else vqq[row][cc] = z;
    }

    const int y0 = blockIdx.x * BH;
    const size_t img_off = (size_t)blockIdx.y * (IMG * IMG);
    const float* __restrict__ xb = x + img_off + tid;   // lane-column base
    const float* __restrict__ yb = y + img_off + tid;

    // Prologue: input rows y0-5 .. y0+4 -> pab[0..9]. gy is block-uniform ->
    // the bounds check is a scalar branch, no per-lane mask code.
    f32x2 pab[14];
    #pragma unroll
    for (int j = 0; j < 10; ++j) {
        int gy = y0 - 5 + j;
        float a = 0.f, b = 0.f;
        if (gy >= 0) { a = xb[gy * IMG]; b = yb[gy * IMG]; }
        pab[j][0] = a + b;
        pab[j][1] = a - b;
    }

    __syncthreads();   // sg + pad zeros visible
    f32x2 g2[11];
    #pragma unroll
    for (int k = 0; k < 11; ++k) { float gv = sg[k]; g2[k][0] = gv; g2[k][1] = gv; }

    const float C1 = 1.0e-4f;
    const float C2 = 9.0e-4f;
    float acc = 0.f;

    const int rr = tid & 3;            // h-conv row: varies within the wave
    const int c0 = (tid >> 2) * 4;     // h-conv output col base (32B aligned)

    for (int k = 0; k < NCHUNK; ++k) {
        const int r0 = y0 + k * CHUNK;

        // Load 4 new input rows r0+5 .. r0+8 -> pab[10..13].
        #pragma unroll
        for (int j = 0; j < 4; ++j) {
            int gy = r0 + 5 + j;      // block-uniform
            float a = 0.f, b = 0.f;
            if (gy < IMG) { a = xb[gy * IMG]; b = yb[gy * IMG]; }
            pab[10 + j][0] = a + b;
            pab[10 + j][1] = a - b;
        }

        // Squares of the 14-row window.
        f32x2 sq[14];
        #pragma unroll
        for (int j = 0; j < 14; ++j) sq[j] = pk_mul(pab[j], pab[j]);

        // Vertical conv: 4 output rows -> LDS (stored col = image col + 5).
        #pragma unroll
        for (int i = 0; i < CHUNK; ++i) {
            f32x2 a = (f32x2)(0.f), q = (f32x2)(0.f);
            #pragma unroll
            for (int t = 0; t < 11; ++t) {
                a = pk_fma(g2[t], pab[i + t], a);
                q = pk_fma(g2[t], sq[i + t], q);
            }
            vab[i][tid + 5] = a;
            vqq[i][tid + 5] = q;
        }

        __syncthreads();

        // Horizontal conv + SSIM: 4 outputs per lane (row rr, cols c0..c0+3).
        // Out col c taps stored cols c..c+10; lane reads stored c0..c0+13.
        {
            f32x2 mu[4], qq[4];
            {
                f32x2 t[14];
                const float4* p = (const float4*)&vab[rr][c0];
                #pragma unroll
                for (int q8 = 0; q8 < 7; ++q8) {
                    float4 f = p[q8];
                    t[2*q8][0] = f.x;  t[2*q8][1] = f.y;
                    t[2*q8+1][0] = f.z;  t[2*q8+1][1] = f.w;
                }
                #pragma unroll
                for (int i = 0; i < 4; ++i) {
                    f32x2 a = (f32x2)(0.f);
                    #pragma unroll
                    for (int t1 = 0; t1 < 11; ++t1) a = pk_fma(g2[t1], t[i + t1], a);
                    mu[i] = a;
                }
            }
            {
                f32x2 t[14];
                const float4* p = (const float4*)&vqq[rr][c0];
                #pragma unroll
                for (int q8 = 0; q8 < 7; ++q8) {
                    float4 f = p[q8];
                    t[2*q8][0] = f.x;  t[2*q8][1] = f.y;
                    t[2*q8+1][0] = f.z;  t[2*q8+1][1] = f.w;
                }
                #pragma unroll
                for (int i = 0; i < 4; ++i) {
                    f32x2 a = (f32x2)(0.f);
                    #pragma unroll
                    for (int t1 = 0; t1 < 11; ++t1) a = pk_fma(g2[t1], t[i + t1], a);
                    qq[i] = a;
                }
            }

            #pragma unroll
            for (int i = 0; i < 4; ++i) {
                // mu[i] = (ms, md); qq[i] = (Ess, Edd)
                f32x2 m2 = pk_mul(mu[i], mu[i]);      // (ms^2, md^2)
                float P = m2[0] + m2[1];              // 2(mxx+myy)
                float Q = m2[0] - m2[1];              // 4 mxy
                float R = qq[i][0] + qq[i][1];        // 2(exx+eyy)
                float S = qq[i][0] - qq[i][1];        // 4 exy
                float num1 = fmaf(0.5f, Q, C1);
                float num2 = fmaf(0.5f, S - Q, C2);
                float den1 = fmaf(0.5f, P, C1);
                float den2 = fmaf(0.5f, R - P, C2);
                acc += (num1 * num2) * __builtin_amdgcn_rcpf(den1 * den2);
            }
        }

        __syncthreads();

        // Slide window down by 4 rows.
        #pragma unroll
        for (int j = 0; j < 10; ++j) pab[j] = pab[j + 4];
    }

    // Block reduction.
    #pragma unroll
    for (int off = 32; off > 0; off >>= 1) acc += __shfl_down(acc, off, 64);
    int wid = tid >> 6, lane = tid & 63;
    if (lane == 0) redbuf[wid] = acc;
    __syncthreads();
    if (tid == 0) {
        float ssum = 0.f;
        #pragma unroll
        for (int w = 0; w < NTHREADS / 64; ++w) ssum += redbuf[w];
        partial[blockIdx.y * gridDim.x + blockIdx.x] = ssum;
    }
}

#define NPART 1024

__global__ __launch_bounds__(512) void ssim_finalize(
    const float* __restrict__ partial, float* __restrict__ out)
{
    __shared__ double red[8];
    double acc = (double)partial[threadIdx.x] + (double)partial[threadIdx.x + 512];
    #pragma unroll
    for (int off = 32; off > 0; off >>= 1) acc += __shfl_down(acc, off, 64);
    int wid = threadIdx.x >> 6, lane = threadIdx.x & 63;
    if (lane == 0) red[wid] = acc;
    __syncthreads();
    if (threadIdx.x == 0) {
        double ssum = 0.0;
        #pragma unroll
        for (int w = 0; w < 8; ++w) ssum += red[w];
        out[0] = (float)(ssum / (64.0 * 512.0 * 512.0));
    }
}

extern "C" void kernel_launch(void* const* d_in, const int* in_sizes, int n_in,
                              void* d_out, int out_size, void* d_ws, size_t ws_size,
                              hipStream_t stream) {
    (void)in_sizes; (void)n_in; (void)out_size; (void)ws_size;
    const float* x   = (const float*)d_in[0];
    const float* y   = (const float*)d_in[1];
    const float* win = (const float*)d_in[2];
    float* out = (float*)d_out;
    float* partial = (float*)d_ws;     // 1024 floats

    dim3 grid(GRIDX, 64);              // 16 x 64 = 1024 blocks, 4 per CU
    ssim_band<<<grid, NTHREADS, 0, stream>>>(x, y, win, partial);
    ssim_finalize<<<1, 512, 0, stream>>>(partial, out);
}

// Round 2
// 170.330 us; speedup vs baseline: 2.3901x; 2.3901x over previous
//
#include <hip/hip_runtime.h>

// Fused SSIM, B=64, C=1, 512x512 fp32, 11x11 separable Gaussian.
// R10 = R9 with the spill fixed. R9's __launch_bounds__(512,8) forced the
// allocator to 32 VGPRs -> 490 MB of scratch spill traffic, VALUBusy 11%.
// R10 reverts to (512,4): compiler allocates naturally (~56-60 VGPR, same
// code class as R8's 60). Since actual VGPR <= 64, HW still runs 8 waves/SIMD;
// with LDS at 33.8 KB -> 4 blocks/CU -> all 32 waves/CU resident. This is the
// occupancy doubling R9 was after, without the register cap.
// Bank class (R6-verified zero-conflict): h-conv rr = tid&3, c0 = (tid>>2)*4;
// row stride 522 f32x2 = 1044 words = 20 mod 32 -> start banks {0,4,..,28},
// 8 lanes each, closed under +16. Writes uniform (tid+5 contiguous).

#define IMG 512
#define BH 32            // band height (output rows per block)
#define CHUNK 4
#define NCHUNK (BH / CHUNK)     // 8
#define SROW 522         // f32x2 per row per plane: 5 pad + 512 + 5 pad
#define NTHREADS 512
#define GRIDX (IMG / BH)        // 16

typedef __attribute__((ext_vector_type(2))) float f32x2;

static __device__ __forceinline__ f32x2 pk_fma(f32x2 a, f32x2 b, f32x2 c) {
    f32x2 d;
    asm("v_pk_fma_f32 %0, %1, %2, %3" : "=v"(d) : "v"(a), "v"(b), "v"(c));
    return d;
}
static __device__ __forceinline__ f32x2 pk_mul(f32x2 a, f32x2 b) {
    f32x2 d;
    asm("v_pk_mul_f32 %0, %1, %2" : "=v"(d) : "v"(a), "v"(b));
    return d;
}

__global__ __launch_bounds__(NTHREADS, 4) void ssim_band(
    const float* __restrict__ x, const float* __restrict__ y,
    const float* __restrict__ win, float* __restrict__ partial)
{
    __shared__ __align__(16) f32x2 vab[CHUNK][SROW];   // v-conv of (s, d)
    __shared__ __align__(16) f32x2 vqq[CHUNK][SROW];   // v-conv of (s^2, d^2)
    __shared__ float sg[11];
    __shared__ float redbuf[NTHREADS / 64];

    const int tid = threadIdx.x;

    // 1D kernel g[i] = row sums of the 2D window (exact since sum(g)==1).
    if (tid < 11) {
        float s = 0.f;
        #pragma unroll
        for (int j = 0; j < 11; ++j) s += win[tid * 11 + j];
        sg[tid] = s;
    }
    // Zero the pad columns once (LDS is re-poisoned every launch).
    // 2 planes * 4 rows * 10 pad cols = 80 entries.
    if (tid < 80) {
        int plane = tid / 40, rem = tid % 40, row = rem / 10, pc = rem % 10;
        int cc = (pc < 5) ? pc : (512 + pc);   // stored cols 0..4, 517..521
        f32x2 z = (f32x2)(0.f);
        if (plane == 0) vab[row][cc] = z; else vqq[row][cc] = z;
    }

    const int y0 = blockIdx.x * BH;
    const size_t img_off = (size_t)blockIdx.y * (IMG * IMG);
    const float* __restrict__ xb = x + img_off + tid;   // lane-column base
    const float* __restrict__ yb = y + img_off + tid;

    // Prologue: input rows y0-5 .. y0+4 -> pab[0..9]. gy is block-uniform ->
    // the bounds check is a scalar branch, no per-lane mask code.
    f32x2 pab[14];
    #pragma unroll
    for (int j = 0; j < 10; ++j) {
        int gy = y0 - 5 + j;
        float a = 0.f, b = 0.f;
        if (gy >= 0) { a = xb[gy * IMG]; b = yb[gy * IMG]; }
        pab[j][0] = a + b;
        pab[j][1] = a - b;
    }

    __syncthreads();   // sg + pad zeros visible
    f32x2 g2[11];
    #pragma unroll
    for (int k = 0; k < 11; ++k) { float gv = sg[k]; g2[k][0] = gv; g2[k][1] = gv; }

    const float C1 = 1.0e-4f;
    const float C2 = 9.0e-4f;
    float acc = 0.f;

    const int rr = tid & 3;            // h-conv row: varies within the wave
    const int c0 = (tid >> 2) * 4;     // h-conv output col base (32B aligned)

    for (int k = 0; k < NCHUNK; ++k) {
        const int r0 = y0 + k * CHUNK;

        // Load 4 new input rows r0+5 .. r0+8 -> pab[10..13].
        #pragma unroll
        for (int j = 0; j < 4; ++j) {
            int gy = r0 + 5 + j;      // block-uniform
            float a = 0.f, b = 0.f;
            if (gy < IMG) { a = xb[gy * IMG]; b = yb[gy * IMG]; }
            pab[10 + j][0] = a + b;
            pab[10 + j][1] = a - b;
        }

        // Squares of the 14-row window.
        f32x2 sq[14];
        #pragma unroll
        for (int j = 0; j < 14; ++j) sq[j] = pk_mul(pab[j], pab[j]);

        // Vertical conv: 4 output rows -> LDS (stored col = image col + 5).
        #pragma unroll
        for (int i = 0; i < CHUNK; ++i) {
            f32x2 a = (f32x2)(0.f), q = (f32x2)(0.f);
            #pragma unroll
            for (int t = 0; t < 11; ++t) {
                a = pk_fma(g2[t], pab[i + t], a);
                q = pk_fma(g2[t], sq[i + t], q);
            }
            vab[i][tid + 5] = a;
            vqq[i][tid + 5] = q;
        }

        __syncthreads();

        // Horizontal conv + SSIM: 4 outputs per lane (row rr, cols c0..c0+3).
        // Out col c taps stored cols c..c+10; lane reads stored c0..c0+13.
        {
            f32x2 mu[4], qq[4];
            {
                f32x2 t[14];
                const float4* p = (const float4*)&vab[rr][c0];
                #pragma unroll
                for (int q8 = 0; q8 < 7; ++q8) {
                    float4 f = p[q8];
                    t[2*q8][0] = f.x;  t[2*q8][1] = f.y;
                    t[2*q8+1][0] = f.z;  t[2*q8+1][1] = f.w;
                }
                #pragma unroll
                for (int i = 0; i < 4; ++i) {
                    f32x2 a = (f32x2)(0.f);
                    #pragma unroll
                    for (int t1 = 0; t1 < 11; ++t1) a = pk_fma(g2[t1], t[i + t1], a);
                    mu[i] = a;
                }
            }
            {
                f32x2 t[14];
                const float4* p = (const float4*)&vqq[rr][c0];
                #pragma unroll
                for (int q8 = 0; q8 < 7; ++q8) {
                    float4 f = p[q8];
                    t[2*q8][0] = f.x;  t[2*q8][1] = f.y;
                    t[2*q8+1][0] = f.z;  t[2*q8+1][1] = f.w;
                }
                #pragma unroll
                for (int i = 0; i < 4; ++i) {
                    f32x2 a = (f32x2)(0.f);
                    #pragma unroll
                    for (int t1 = 0; t1 < 11; ++t1) a = pk_fma(g2[t1], t[i + t1], a);
                    qq[i] = a;
                }
            }

            #pragma unroll
            for (int i = 0; i < 4; ++i) {
                // mu[i] = (ms, md); qq[i] = (Ess, Edd)
                f32x2 m2 = pk_mul(mu[i], mu[i]);      // (ms^2, md^2)
                float P = m2[0] + m2[1];              // 2(mxx+myy)
                float Q = m2[0] - m2[1];              // 4 mxy
                float R = qq[i][0] + qq[i][1];        // 2(exx+eyy)
                float S = qq[i][0] - qq[i][1];        // 4 exy
                float num1 = fmaf(0.5f, Q, C1);
                float num2 = fmaf(0.5f, S - Q, C2);
                float den1 = fmaf(0.5f, P, C1);
                float den2 = fmaf(0.5f, R - P, C2);
                acc += (num1 * num2) * __builtin_amdgcn_rcpf(den1 * den2);
            }
        }

        __syncthreads();

        // Slide window down by 4 rows.
        #pragma unroll
        for (int j = 0; j < 10; ++j) pab[j] = pab[j + 4];
    }

    // Block reduction.
    #pragma unroll
    for (int off = 32; off > 0; off >>= 1) acc += __shfl_down(acc, off, 64);
    int wid = tid >> 6, lane = tid & 63;
    if (lane == 0) redbuf[wid] = acc;
    __syncthreads();
    if (tid == 0) {
        float ssum = 0.f;
        #pragma unroll
        for (int w = 0; w < NTHREADS / 64; ++w) ssum += redbuf[w];
        partial[blockIdx.y * gridDim.x + blockIdx.x] = ssum;
    }
}

__global__ __launch_bounds__(512) void ssim_finalize(
    const float* __restrict__ partial, float* __restrict__ out)
{
    __shared__ double red[8];
    double acc = (double)partial[threadIdx.x] + (double)partial[threadIdx.x + 512];
    #pragma unroll
    for (int off = 32; off > 0; off >>= 1) acc += __shfl_down(acc, off, 64);
    int wid = threadIdx.x >> 6, lane = threadIdx.x & 63;
    if (lane == 0) red[wid] = acc;
    __syncthreads();
    if (threadIdx.x == 0) {
        double ssum = 0.0;
        #pragma unroll
        for (int w = 0; w < 8; ++w) ssum += red[w];
        out[0] = (float)(ssum / (64.0 * 512.0 * 512.0));
    }
}

extern "C" void kernel_launch(void* const* d_in, const int* in_sizes, int n_in,
                              void* d_out, int out_size, void* d_ws, size_t ws_size,
                              hipStream_t stream) {
    (void)in_sizes; (void)n_in; (void)out_size; (void)ws_size;
    const float* x   = (const float*)d_in[0];
    const float* y   = (const float*)d_in[1];
    const float* win = (const float*)d_in[2];
    float* out = (float*)d_out;
    float* partial = (float*)d_ws;     // 1024 floats

    dim3 grid(GRIDX, 64);              // 16 x 64 = 1024 blocks, 4 per CU
    ssim_band<<<grid, NTHREADS, 0, stream>>>(x, y, win, partial);
    ssim_finalize<<<1, 512, 0, stream>>>(partial, out);
}

// Round 3
// 166.055 us; speedup vs baseline: 2.4516x; 1.0257x over previous
//
#include <hip/hip_runtime.h>

// Fused SSIM, B=64, C=1, 512x512 fp32, 11x11 separable Gaussian.
// R11 = R10 + double-buffered LDS, ONE barrier per chunk.
// R8/R10 post-mortem: VALUBusy pinned at ~50% for both 2 and 4 blocks/CU ->
// occupancy was never the limit; the 2-barriers-per-chunk lockstep was.
// Per span: {shift, load 4 rows, v-conv(k+1) -> write buf ~B} || {h-conv(k) +
// SSIM <- read buf B}; single __syncthreads() at span end protects BOTH
// hazards (RAW on read buf: written last span; WAR on write buf: read last
// span). Two independent FMA chains per span ~doubles schedulable ILP at half
// the barrier count. LDS 66.8 KB -> 2 blocks/CU (R8/R10 showed 2 vs 4
// blocks/CU is perf-neutral).
// Known flat tax: every h-conv ds_read_b128 pays exactly 2x (conflict counter
// == min read cycles, bit-exact in R8 & R10) — ~9% of cycles, addressed later
// if it surfaces as the new wall.

#define IMG 512
#define BH 32            // band height (output rows per block)
#define CHUNK 4
#define NCHUNK (BH / CHUNK)     // 8
#define SROW 522         // f32x2 per row per plane: 5 pad + 512 + 5 pad
#define NTHREADS 512
#define GRIDX (IMG / BH)        // 16

typedef __attribute__((ext_vector_type(2))) float f32x2;

static __device__ __forceinline__ f32x2 pk_fma(f32x2 a, f32x2 b, f32x2 c) {
    f32x2 d;
    asm("v_pk_fma_f32 %0, %1, %2, %3" : "=v"(d) : "v"(a), "v"(b), "v"(c));
    return d;
}
static __device__ __forceinline__ f32x2 pk_mul(f32x2 a, f32x2 b) {
    f32x2 d;
    asm("v_pk_mul_f32 %0, %1, %2" : "=v"(d) : "v"(a), "v"(b));
    return d;
}

__global__ __launch_bounds__(NTHREADS, 4) void ssim_band(
    const float* __restrict__ x, const float* __restrict__ y,
    const float* __restrict__ win, float* __restrict__ partial)
{
    // Double-buffered v-conv planes; separate named arrays keep buffer
    // selection static (no runtime-index aliasing for the compiler).
    __shared__ __align__(16) f32x2 vab0[CHUNK][SROW];
    __shared__ __align__(16) f32x2 vqq0[CHUNK][SROW];
    __shared__ __align__(16) f32x2 vab1[CHUNK][SROW];
    __shared__ __align__(16) f32x2 vqq1[CHUNK][SROW];
    __shared__ float sg[11];
    __shared__ float redbuf[NTHREADS / 64];

    const int tid = threadIdx.x;

    // 1D kernel g[i] = row sums of the 2D window (exact since sum(g)==1).
    if (tid < 11) {
        float s = 0.f;
        #pragma unroll
        for (int j = 0; j < 11; ++j) s += win[tid * 11 + j];
        sg[tid] = s;
    }
    // Zero the pad columns once (LDS is re-poisoned every launch).
    // 2 bufs * 2 planes * 4 rows * 10 pad cols = 160 entries.
    if (tid < 160) {
        int buf = tid / 80, rem = tid % 80;
        int plane = rem / 40, rem2 = rem % 40, row = rem2 / 10, pc = rem2 % 10;
        int cc = (pc < 5) ? pc : (512 + pc);   // stored cols 0..4, 517..521
        f32x2 z = (f32x2)(0.f);
        if (buf == 0) { if (plane == 0) vab0[row][cc] = z; else vqq0[row][cc] = z; }
        else          { if (plane == 0) vab1[row][cc] = z; else vqq1[row][cc] = z; }
    }

    const int y0 = blockIdx.x * BH;
    const size_t img_off = (size_t)blockIdx.y * (IMG * IMG);
    const float* __restrict__ xb = x + img_off + tid;   // lane-column base
    const float* __restrict__ yb = y + img_off + tid;

    // Prologue: input rows y0-5 .. y0+8 -> pab[0..13] (chunk 0 window).
    // gy is block-uniform -> scalar branch, no per-lane mask code.
    f32x2 pab[14];
    #pragma unroll
    for (int j = 0; j < 14; ++j) {
        int gy = y0 - 5 + j;
        float a = 0.f, b = 0.f;
        if (gy >= 0) { a = xb[gy * IMG]; b = yb[gy * IMG]; }
        pab[j][0] = a + b;
        pab[j][1] = a - b;
    }

    __syncthreads();   // sg visible (pads also done)
    f32x2 g2[11];
    #pragma unroll
    for (int k = 0; k < 11; ++k) { float gv = sg[k]; g2[k][0] = gv; g2[k][1] = gv; }

    // v-conv chunk 0 -> buf0.
    {
        f32x2 sq[14];
        #pragma unroll
        for (int j = 0; j < 14; ++j) sq[j] = pk_mul(pab[j], pab[j]);
        #pragma unroll
        for (int i = 0; i < CHUNK; ++i) {
            f32x2 a = (f32x2)(0.f), q = (f32x2)(0.f);
            #pragma unroll
            for (int t = 0; t < 11; ++t) {
                a = pk_fma(g2[t], pab[i + t], a);
                q = pk_fma(g2[t], sq[i + t], q);
            }
            vab0[i][tid + 5] = a;
            vqq0[i][tid + 5] = q;
        }
    }
    __syncthreads();   // buf0 visible

    const float C1 = 1.0e-4f;
    const float C2 = 9.0e-4f;
    float acc = 0.f;

    const int rr = tid & 3;            // h-conv row: varies within the wave
    const int c0 = (tid >> 2) * 4;     // h-conv output col base (32B aligned)

    // One span: v-conv(k+1) into (wab,wqq) overlapped with h-conv(k) from
    // (rab,rqq); single barrier at the end.
    auto span = [&](int k,
                    f32x2 (&rab)[CHUNK][SROW], f32x2 (&rqq)[CHUNK][SROW],
                    f32x2 (&wab)[CHUNK][SROW], f32x2 (&wqq)[CHUNK][SROW]) {
        if (k < NCHUNK - 1) {
            // Slide window down 4 rows; load rows y0+4k+9 .. y0+4k+12.
            #pragma unroll
            for (int j = 0; j < 10; ++j) pab[j] = pab[j + 4];
            int rbase = y0 + 4 * k + 9;
            #pragma unroll
            for (int j = 0; j < 4; ++j) {
                int gy = rbase + j;      // block-uniform
                float a = 0.f, b = 0.f;
                if (gy < IMG) { a = xb[gy * IMG]; b = yb[gy * IMG]; }
                pab[10 + j][0] = a + b;
                pab[10 + j][1] = a - b;
            }
            f32x2 sq[14];
            #pragma unroll
            for (int j = 0; j < 14; ++j) sq[j] = pk_mul(pab[j], pab[j]);
            #pragma unroll
            for (int i = 0; i < CHUNK; ++i) {
                f32x2 a = (f32x2)(0.f), q = (f32x2)(0.f);
                #pragma unroll
                for (int t = 0; t < 11; ++t) {
                    a = pk_fma(g2[t], pab[i + t], a);
                    q = pk_fma(g2[t], sq[i + t], q);
                }
                wab[i][tid + 5] = a;
                wqq[i][tid + 5] = q;
            }
        }

        // h-conv + SSIM: 4 outputs per lane (row rr, cols c0..c0+3).
        {
            f32x2 mu[4], qq[4];
            {
                f32x2 t[14];
                const float4* p = (const float4*)&rab[rr][c0];
                #pragma unroll
                for (int q8 = 0; q8 < 7; ++q8) {
                    float4 f = p[q8];
                    t[2*q8][0] = f.x;  t[2*q8][1] = f.y;
                    t[2*q8+1][0] = f.z;  t[2*q8+1][1] = f.w;
                }
                #pragma unroll
                for (int i = 0; i < 4; ++i) {
                    f32x2 a = (f32x2)(0.f);
                    #pragma unroll
                    for (int t1 = 0; t1 < 11; ++t1) a = pk_fma(g2[t1], t[i + t1], a);
                    mu[i] = a;
                }
            }
            {
                f32x2 t[14];
                const float4* p = (const float4*)&rqq[rr][c0];
                #pragma unroll
                for (int q8 = 0; q8 < 7; ++q8) {
                    float4 f = p[q8];
                    t[2*q8][0] = f.x;  t[2*q8][1] = f.y;
                    t[2*q8+1][0] = f.z;  t[2*q8+1][1] = f.w;
                }
                #pragma unroll
                for (int i = 0; i < 4; ++i) {
                    f32x2 a = (f32x2)(0.f);
                    #pragma unroll
                    for (int t1 = 0; t1 < 11; ++t1) a = pk_fma(g2[t1], t[i + t1], a);
                    qq[i] = a;
                }
            }

            #pragma unroll
            for (int i = 0; i < 4; ++i) {
                // mu[i] = (ms, md); qq[i] = (Ess, Edd)
                f32x2 m2 = pk_mul(mu[i], mu[i]);      // (ms^2, md^2)
                float P = m2[0] + m2[1];              // 2(mxx+myy)
                float Q = m2[0] - m2[1];              // 4 mxy
                float R = qq[i][0] + qq[i][1];        // 2(exx+eyy)
                float S = qq[i][0] - qq[i][1];        // 4 exy
                float num1 = fmaf(0.5f, Q, C1);
                float num2 = fmaf(0.5f, S - Q, C2);
                float den1 = fmaf(0.5f, P, C1);
                float den2 = fmaf(0.5f, R - P, C2);
                acc += (num1 * num2) * __builtin_amdgcn_rcpf(den1 * den2);
            }
        }

        if (k < NCHUNK - 1) __syncthreads();
    };

    #pragma unroll 1
    for (int kk = 0; kk < NCHUNK; kk += 2) {
        span(kk,     vab0, vqq0, vab1, vqq1);
        span(kk + 1, vab1, vqq1, vab0, vqq0);
    }

    // Block reduction.
    #pragma unroll
    for (int off = 32; off > 0; off >>= 1) acc += __shfl_down(acc, off, 64);
    int wid = tid >> 6, lane = tid & 63;
    if (lane == 0) redbuf[wid] = acc;
    __syncthreads();
    if (tid == 0) {
        float ssum = 0.f;
        #pragma unroll
        for (int w = 0; w < NTHREADS / 64; ++w) ssum += redbuf[w];
        partial[blockIdx.y * gridDim.x + blockIdx.x] = ssum;
    }
}

__global__ __launch_bounds__(512) void ssim_finalize(
    const float* __restrict__ partial, float* __restrict__ out)
{
    __shared__ double red[8];
    double acc = (double)partial[threadIdx.x] + (double)partial[threadIdx.x + 512];
    #pragma unroll
    for (int off = 32; off > 0; off >>= 1) acc += __shfl_down(acc, off, 64);
    int wid = threadIdx.x >> 6, lane = threadIdx.x & 63;
    if (lane == 0) red[wid] = acc;
    __syncthreads();
    if (threadIdx.x == 0) {
        double ssum = 0.0;
        #pragma unroll
        for (int w = 0; w < 8; ++w) ssum += red[w];
        out[0] = (float)(ssum / (64.0 * 512.0 * 512.0));
    }
}

extern "C" void kernel_launch(void* const* d_in, const int* in_sizes, int n_in,
                              void* d_out, int out_size, void* d_ws, size_t ws_size,
                              hipStream_t stream) {
    (void)in_sizes; (void)n_in; (void)out_size; (void)ws_size;
    const float* x   = (const float*)d_in[0];
    const float* y   = (const float*)d_in[1];
    const float* win = (const float*)d_in[2];
    float* out = (float*)d_out;
    float* partial = (float*)d_ws;     // 1024 floats

    dim3 grid(GRIDX, 64);              // 16 x 64 = 1024 blocks
    ssim_band<<<grid, NTHREADS, 0, stream>>>(x, y, win, partial);
    ssim_finalize<<<1, 512, 0, stream>>>(partial, out);
}